// Round 4
// baseline (736.600 us; speedup 1.0000x reference)
//
#include <hip/hip_runtime.h>
#include <hip/hip_bf16.h>

typedef unsigned int uint;
typedef unsigned short ushort;

// bf16 bit-level conversions (RNE pack, exact unpack) for internal z/h storage
static __device__ __forceinline__ ushort f2b(float f) {
    uint u = __float_as_uint(f);
    uint r = (u + 0x7FFFu + ((u >> 16) & 1u)) >> 16;
    return (ushort)r;
}
static __device__ __forceinline__ float b2f_u(ushort h) { return __uint_as_float(((uint)h) << 16); }

// ---------------- wave-level inclusive scan (64 lanes) ----------------
static __device__ __forceinline__ unsigned wave_incl_scan(unsigned v) {
    int lane = threadIdx.x & 63;
    #pragma unroll
    for (int d = 1; d < 64; d <<= 1) {
        unsigned t = (unsigned)__shfl_up((int)v, d, 64);
        if (lane >= d) v += t;
    }
    return v;
}

// mode 0: value = srcu[idx];  mode 1: value = (node_type[idx]==0)
__global__ __launch_bounds__(1024) void scan1_kernel(const unsigned* srcu, const int* nt,
                                                     unsigned* out, unsigned* blocksum, int n,
                                                     int mode) {
    __shared__ unsigned wsum[16];
    int idx = blockIdx.x * 1024 + threadIdx.x;
    unsigned v = 0;
    if (idx < n) v = (mode == 0) ? srcu[idx] : (nt[idx] == 0 ? 1u : 0u);
    unsigned incl = wave_incl_scan(v);
    int wid = threadIdx.x >> 6, lane = threadIdx.x & 63;
    if (lane == 63) wsum[wid] = incl;
    __syncthreads();
    if (threadIdx.x < 64) {
        unsigned wv = (threadIdx.x < 16) ? wsum[threadIdx.x] : 0u;
        unsigned ws = wave_incl_scan(wv);
        if (threadIdx.x < 16) wsum[threadIdx.x] = ws - wv;
    }
    __syncthreads();
    unsigned excl = incl - v + wsum[wid];
    if (idx < n) out[idx] = excl;
    if (threadIdx.x == 1023) blocksum[blockIdx.x] = excl + v;
}

__global__ __launch_bounds__(1024) void scan2_kernel(const unsigned* blocksum, unsigned* blockoff, int nb) {
    __shared__ unsigned wsum[16];
    int t = threadIdx.x;
    unsigned v = (t < nb) ? blocksum[t] : 0u;
    unsigned incl = wave_incl_scan(v);
    int wid = t >> 6, lane = t & 63;
    if (lane == 63) wsum[wid] = incl;
    __syncthreads();
    if (t < 64) {
        unsigned wv = (t < 16) ? wsum[t] : 0u;
        unsigned ws = wave_incl_scan(wv);
        if (t < 16) wsum[t] = ws - wv;
    }
    __syncthreads();
    if (t < nb) blockoff[t] = incl - v + wsum[wid];
}

__global__ void scan3_kernel(unsigned* out, const unsigned* blockoff, int n) {
    int idx = blockIdx.x * blockDim.x + threadIdx.x;
    if (idx < n) out[idx] += blockoff[idx >> 10];
}

// ---------------- CSR build ----------------
__global__ void hist_kernel(const int* dst, unsigned* deg, int E, int N) {
    int e = blockIdx.x * 256 + threadIdx.x;
    if (e < E) {
        int d = dst[e];
        if ((unsigned)d < (unsigned)N) atomicAdd(&deg[d], 1u);
    }
}

__global__ void dinv_kernel(const unsigned* deg, float* dinv, int n) {
    int i = blockIdx.x * 256 + threadIdx.x;
    if (i < n) dinv[i] = rsqrtf((float)(deg[i] + 1u));  // +1 self loop
}

__global__ void fill_kernel(const int* src, const int* dst, const unsigned* off, unsigned* cnt,
                            int* csr_src, int E, int N) {
    int e = blockIdx.x * 256 + threadIdx.x;
    if (e < E) {
        int s = src[e];
        int d = dst[e];
        if ((unsigned)d < (unsigned)N && (unsigned)s < (unsigned)N) {
            unsigned p = off[d] + atomicAdd(&cnt[d], 1u);
            if (p < (unsigned)E) csr_src[p] = s;
        }
    }
}

// ---------------- layer-1 GEMM: z = (x @ W1) * dinv[row], bf16 out ----------------
__global__ __launch_bounds__(256) void gemm1_kernel(const float* x, const float* W1,
                                                    const float* dinv, ushort* zb, int n) {
    __shared__ float Ws[96];
    if (threadIdx.x < 96) Ws[threadIdx.x] = W1[threadIdx.x];
    __syncthreads();
    int i = blockIdx.x * 256 + threadIdx.x;
    if (i >= n) return;
    float x0 = x[i * 3], x1 = x[i * 3 + 1], x2 = x[i * 3 + 2];
    float di = dinv[i];
    uint pk[16];
    #pragma unroll
    for (int q = 0; q < 16; q++) {
        int j0 = 2 * q, j1 = 2 * q + 1;
        float o0 = (x0 * Ws[j0] + x1 * Ws[32 + j0] + x2 * Ws[64 + j0]) * di;
        float o1 = (x0 * Ws[j1] + x1 * Ws[32 + j1] + x2 * Ws[64 + j1]) * di;
        pk[q] = (uint)f2b(o0) | ((uint)f2b(o1) << 16);
    }
    uint4* zp = (uint4*)(zb + (size_t)i * 32);
    #pragma unroll
    for (int r = 0; r < 4; r++) zp[r] = make_uint4(pk[4*r], pk[4*r+1], pk[4*r+2], pk[4*r+3]);
}

// ---------------- folded GEMM: z = (h @ Wf + cf) * dinv[row], bf16 in/out ----------------
__global__ __launch_bounds__(256) void gemmf_kernel(const ushort* hb, const float* Wf, const float* cf,
                                                    const float* dinv, ushort* zb, int n) {
    __shared__ float Ws[1024];
    __shared__ float cs[32];
    ((float4*)Ws)[threadIdx.x] = ((const float4*)Wf)[threadIdx.x];
    if (threadIdx.x < 32) cs[threadIdx.x] = cf[threadIdx.x];
    __syncthreads();
    int i = blockIdx.x * 256 + threadIdx.x;
    if (i >= n) return;
    const uint4* hp = (const uint4*)(hb + (size_t)i * 32);
    float hk[32];
    #pragma unroll
    for (int r = 0; r < 4; r++) {
        uint4 v = hp[r];
        hk[r*8+0] = b2f_u(v.x & 0xFFFF); hk[r*8+1] = b2f_u(v.x >> 16);
        hk[r*8+2] = b2f_u(v.y & 0xFFFF); hk[r*8+3] = b2f_u(v.y >> 16);
        hk[r*8+4] = b2f_u(v.z & 0xFFFF); hk[r*8+5] = b2f_u(v.z >> 16);
        hk[r*8+6] = b2f_u(v.w & 0xFFFF); hk[r*8+7] = b2f_u(v.w >> 16);
    }
    float acc[32];
    #pragma unroll
    for (int j = 0; j < 32; j++) acc[j] = cs[j];
    #pragma unroll
    for (int k = 0; k < 32; k++) {
        float h0 = hk[k];
        #pragma unroll
        for (int j = 0; j < 32; j++) acc[j] += h0 * Ws[k * 32 + j];
    }
    float di = dinv[i];
    uint pk[16];
    #pragma unroll
    for (int q = 0; q < 16; q++)
        pk[q] = (uint)f2b(acc[2*q] * di) | ((uint)f2b(acc[2*q+1] * di) << 16);
    uint4* zp = (uint4*)(zb + (size_t)i * 32);
    #pragma unroll
    for (int r = 0; r < 4; r++) zp[r] = make_uint4(pk[4*r], pk[4*r+1], pk[4*r+2], pk[4*r+3]);
}

// ---------------- aggregate: h = relu(dinv[d]*(sum z[src] + z[d]) + b), bf16 in/out ----------------
__global__ __launch_bounds__(256) void agg_kernel(const ushort* zb, const int* csr_src,
                                                  const unsigned* off, const float* dinv,
                                                  const float* bias, ushort* hb, int n, int E,
                                                  int mode, float* stats_sum, float* stats_sq,
                                                  float* rowsum, unsigned* maxkey) {
    int lane = threadIdx.x & 31;
    int grp = threadIdx.x >> 5;
    int stride = gridDim.x * 8;
    float bv = bias[lane];
    float bsum = 0.f, bsq = 0.f, lmax = -3.0e38f;
    for (int node = blockIdx.x * 8 + grp; node < n; node += stride) {
        unsigned s = off[node];
        unsigned e = (node + 1 < n) ? off[node + 1] : (unsigned)E;
        if (e > (unsigned)E) e = (unsigned)E;
        if (s > e) s = e;
        float acc = b2f_u(zb[(size_t)node * 32 + lane]);   // self loop
        unsigned p = s;
        for (; p + 4 <= e; p += 4) {
            unsigned s0 = (unsigned)csr_src[p];
            unsigned s1 = (unsigned)csr_src[p + 1];
            unsigned s2 = (unsigned)csr_src[p + 2];
            unsigned s3 = (unsigned)csr_src[p + 3];
            float v0 = (s0 < (unsigned)n) ? b2f_u(zb[(size_t)s0 * 32 + lane]) : 0.f;
            float v1 = (s1 < (unsigned)n) ? b2f_u(zb[(size_t)s1 * 32 + lane]) : 0.f;
            float v2 = (s2 < (unsigned)n) ? b2f_u(zb[(size_t)s2 * 32 + lane]) : 0.f;
            float v3 = (s3 < (unsigned)n) ? b2f_u(zb[(size_t)s3 * 32 + lane]) : 0.f;
            acc += (v0 + v1) + (v2 + v3);
        }
        for (; p < e; ++p) {
            unsigned s0 = (unsigned)csr_src[p];
            if (s0 < (unsigned)n) acc += b2f_u(zb[(size_t)s0 * 32 + lane]);
        }
        float hval = fmaxf(dinv[node] * acc + bv, 0.f);
        hb[(size_t)node * 32 + lane] = f2b(hval);
        if (mode == 0) {
            bsum += hval; bsq += hval * hval;
        } else {
            float rs = hval;
            #pragma unroll
            for (int d = 1; d < 32; d <<= 1) rs += __shfl_xor(rs, d, 32);
            if (lane == 0) { rowsum[node] = rs; lmax = fmaxf(lmax, rs); }
        }
    }
    if (mode == 0) {
        __shared__ float ls[256], lq[256];
        ls[threadIdx.x] = bsum; lq[threadIdx.x] = bsq;
        __syncthreads();
        if (threadIdx.x < 32) {
            float a = 0.f, b = 0.f;
            #pragma unroll
            for (int g = 0; g < 8; g++) { a += ls[threadIdx.x + 32 * g]; b += lq[threadIdx.x + 32 * g]; }
            atomicAdd(&stats_sum[threadIdx.x], a);
            atomicAdd(&stats_sq[threadIdx.x], b);
        }
    } else {
        __shared__ float lm[256];
        lm[threadIdx.x] = lmax;
        __syncthreads();
        if (threadIdx.x == 0) {
            float m = -3.0e38f;
            for (int t = 0; t < 256; t += 32) m = fmaxf(m, lm[t]);
            unsigned u = __float_as_uint(m);
            unsigned key = (u & 0x80000000u) ? ~u : (u | 0x80000000u);
            atomicMax(maxkey, key);
        }
    }
}

// ---------------- fold BN into next layer's weights ----------------
__global__ void fold_kernel(float* stats_sum, float* stats_sq, const float* g, const float* be,
                            const float* W, float* Wf, float* cf, int n) {
    __shared__ float a_s[32], d_s[32];
    int t = threadIdx.x;
    if (t < 32) {
        float mu = stats_sum[t] / (float)n;
        float var = fmaxf(stats_sq[t] / (float)n - mu * mu, 0.f);
        float a = g[t] * rsqrtf(var + 1e-5f);
        float d = be[t] - mu * a;
        a_s[t] = a; d_s[t] = d;
        stats_sum[t] = 0.f; stats_sq[t] = 0.f;
    }
    __syncthreads();
    if (t < 32) {
        float c = 0.f;
        for (int k = 0; k < 32; k++) {
            float w = W[k * 32 + t];
            Wf[k * 32 + t] = a_s[k] * w;
            c += d_s[k] * w;
        }
        cf[t] = c;
    }
}

// ---------------- softmax-weighted pooling ----------------
__global__ __launch_bounds__(256) void pool_kernel(const ushort* hb, const float* rowsum,
                                                   const unsigned* maxkey, float* gvec, float* Zp,
                                                   int n) {
    unsigned key = *maxkey;
    float M = 0.f;
    if (key != 0u) M = (key & 0x80000000u) ? __uint_as_float(key ^ 0x80000000u) : __uint_as_float(~key);
    int lane = threadIdx.x & 31;
    int grp = threadIdx.x >> 5;
    int stride = gridDim.x * 8;
    float accZ = 0.f, accg = 0.f;
    for (int node = blockIdx.x * 8 + grp; node < n; node += stride) {
        float e = __expf(rowsum[node] - M);
        accg += b2f_u(hb[(size_t)node * 32 + lane]) * e;
        if (lane == 0) accZ += e;
    }
    __shared__ float ls[256];
    ls[threadIdx.x] = accg;
    __syncthreads();
    if (threadIdx.x < 32) {
        float a = 0.f;
        #pragma unroll
        for (int g = 0; g < 8; g++) a += ls[threadIdx.x + 32 * g];
        atomicAdd(&gvec[threadIdx.x], a);
    }
    __syncthreads();
    ls[threadIdx.x] = (lane == 0) ? accZ : 0.f;
    __syncthreads();
    if (threadIdx.x == 0) {
        float a = 0.f;
        for (int t = 0; t < 256; t += 32) a += ls[t];
        atomicAdd(Zp, a);
    }
}

// ---------------- graph head (float32 out!) ----------------
__global__ void dn_kernel(const float* gvec, const float* Zp, const float* Wd1, const float* bd1,
                          const float* Wd2, const float* bd2, float* out, int C) {
    __shared__ float ge[32], tt[16];
    int t = threadIdx.x;
    float Z = fmaxf(*Zp, 1e-30f);
    if (t < 32) ge[t] = gvec[t] / Z;
    __syncthreads();
    if (t < 16) {
        float s = bd1[t];
        for (int k = 0; k < 32; k++) s += ge[k] * Wd1[k * 16 + t];
        tt[t] = fmaxf(s, 0.f);
    }
    __syncthreads();
    if (t == 0) {
        float s = bd2[0];
        for (int j = 0; j < 16; j++) s += tt[j] * Wd2[j];
        out[C] = fminf(fmaxf(s, -1000.f), 1000.f);   // defensive bound
    }
}

// ---------------- candidate head (float32 out!) ----------------
__global__ __launch_bounds__(256) void cand_kernel(const ushort* hb, const int* nt,
                                                   const unsigned* pos, const float* Wc1,
                                                   const float* bc1, const float* Wc2,
                                                   const float* bc2, float* out, int n, int C) {
    __shared__ float W1s[512], b1s[16], W2s[16];
    for (int t = threadIdx.x; t < 512; t += 256) W1s[t] = Wc1[t];
    if (threadIdx.x < 16) { b1s[threadIdx.x] = bc1[threadIdx.x]; W2s[threadIdx.x] = Wc2[threadIdx.x]; }
    __syncthreads();
    int i = blockIdx.x * 256 + threadIdx.x;
    if (i >= n) return;
    if (nt[i] != 0) return;
    const uint4* hp = (const uint4*)(hb + (size_t)i * 32);
    float hv[32];
    #pragma unroll
    for (int r = 0; r < 4; r++) {
        uint4 v = hp[r];
        hv[r*8+0] = b2f_u(v.x & 0xFFFF); hv[r*8+1] = b2f_u(v.x >> 16);
        hv[r*8+2] = b2f_u(v.y & 0xFFFF); hv[r*8+3] = b2f_u(v.y >> 16);
        hv[r*8+4] = b2f_u(v.z & 0xFFFF); hv[r*8+5] = b2f_u(v.z >> 16);
        hv[r*8+6] = b2f_u(v.w & 0xFFFF); hv[r*8+7] = b2f_u(v.w >> 16);
    }
    float s = bc2[0];
    #pragma unroll
    for (int j = 0; j < 16; j++) {
        float u = b1s[j];
        #pragma unroll
        for (int k = 0; k < 32; k++) u += hv[k] * W1s[k * 16 + j];
        s += fmaxf(u, 0.f) * W2s[j];
    }
    s = fminf(fmaxf(s, -1000.f), 1000.f);   // defensive bound
    unsigned p = pos[i];
    if (p < (unsigned)C) {
        out[p] = s;                  // logits chunk [0..C-1]
        out[C + 1 + p] = (float)i;   // index chunk  [C+1..2C]
    }
}

// ---------------- host launch ----------------
extern "C" void kernel_launch(void* const* d_in, const int* in_sizes, int n_in,
                              void* d_out, int out_size, void* d_ws, size_t ws_size,
                              hipStream_t stream) {
    const float* x   = (const float*)d_in[0];
    const int*   ei  = (const int*)d_in[1];    // int64 -> int32 per harness
    const int*   nt  = (const int*)d_in[2];
    const float* W1  = (const float*)d_in[3];  const float* b1  = (const float*)d_in[4];
    const float* W2  = (const float*)d_in[5];  const float* b2  = (const float*)d_in[6];
    const float* W3  = (const float*)d_in[7];  const float* b3  = (const float*)d_in[8];
    const float* g1  = (const float*)d_in[9];  const float* be1 = (const float*)d_in[10];
    const float* g2  = (const float*)d_in[11]; const float* be2 = (const float*)d_in[12];
    const float* Wc1 = (const float*)d_in[13]; const float* bc1 = (const float*)d_in[14];
    const float* Wc2 = (const float*)d_in[15]; const float* bc2 = (const float*)d_in[16];
    const float* Wd1 = (const float*)d_in[17]; const float* bd1 = (const float*)d_in[18];
    const float* Wd2 = (const float*)d_in[19]; const float* bd2 = (const float*)d_in[20];

    const int N = in_sizes[0] / 3;
    const int E = in_sizes[1] / 2;
    const int C = (out_size - 1) / 2;
    const int* e_src = ei;
    const int* e_dst = ei + E;
    float* out = (float*)d_out;

    // ---- workspace carve-up: ~21 MB ----
    char* w = (char*)d_ws;
    auto alloc = [&](size_t bytes) { void* p = (void*)w; w += (bytes + 255) & ~(size_t)255; return p; };
    float*    stats    = (float*)alloc(256 * 4);
    float*    Wf       = (float*)alloc(1024 * 4);
    float*    cf       = (float*)alloc(32 * 4);
    unsigned* blocksum = (unsigned*)alloc(1024 * 4);
    unsigned* blockoff = (unsigned*)alloc(1024 * 4);
    float*    dinv     = (float*)alloc((size_t)N * 4);
    unsigned* csr_off  = (unsigned*)alloc((size_t)N * 4);
    unsigned* cand_pos = (unsigned*)alloc((size_t)N * 4);
    unsigned* deg      = (unsigned*)alloc((size_t)N * 4);
    unsigned* cnt      = (unsigned*)alloc((size_t)N * 4);   // reused as rowsum after CSR build
    int*      csr_src  = (int*)alloc((size_t)E * 4);
    ushort*   zb       = (ushort*)alloc((size_t)N * 32 * 2);
    ushort*   hb       = (ushort*)alloc((size_t)N * 32 * 2);

    float* stats_sum = stats;
    float* stats_sq  = stats + 32;
    float* gvec      = stats + 64;
    float* Zp        = stats + 96;
    unsigned* maxkey = (unsigned*)(stats + 97);
    float* rowsum    = (float*)cnt;   // cnt finished (fill) before rowsum written (layer-3 agg)

    hipMemsetAsync(stats, 0, 256 * 4, stream);
    hipMemsetAsync(deg, 0, (size_t)N * 4, stream);
    hipMemsetAsync(cnt, 0, (size_t)N * 4, stream);

    const int nb1 = (N + 1023) / 1024;
    const int gN  = (N + 255) / 256;
    const int gE  = (E + 255) / 256;

    // ---- CSR build ----
    hipLaunchKernelGGL(hist_kernel, dim3(gE), dim3(256), 0, stream, e_dst, deg, E, N);
    hipLaunchKernelGGL(dinv_kernel, dim3(gN), dim3(256), 0, stream, deg, dinv, N);
    hipLaunchKernelGGL(scan1_kernel, dim3(nb1), dim3(1024), 0, stream, deg, (const int*)nullptr, csr_off, blocksum, N, 0);
    hipLaunchKernelGGL(scan2_kernel, dim3(1), dim3(1024), 0, stream, blocksum, blockoff, nb1);
    hipLaunchKernelGGL(scan3_kernel, dim3(gN), dim3(256), 0, stream, csr_off, blockoff, N);
    hipLaunchKernelGGL(fill_kernel, dim3(gE), dim3(256), 0, stream, e_src, e_dst, csr_off, cnt, csr_src, E, N);

    // ---- candidate position scan ----
    hipLaunchKernelGGL(scan1_kernel, dim3(nb1), dim3(1024), 0, stream, (const unsigned*)nullptr, nt, cand_pos, blocksum, N, 1);
    hipLaunchKernelGGL(scan2_kernel, dim3(1), dim3(1024), 0, stream, blocksum, blockoff, nb1);
    hipLaunchKernelGGL(scan3_kernel, dim3(gN), dim3(256), 0, stream, cand_pos, blockoff, N);

    const int AGG_BLOCKS = 1024;

    // ---- layer 1 ----
    hipLaunchKernelGGL(gemm1_kernel, dim3(gN), dim3(256), 0, stream, x, W1, dinv, zb, N);
    hipLaunchKernelGGL(agg_kernel, dim3(AGG_BLOCKS), dim3(256), 0, stream, zb, csr_src, csr_off,
                       dinv, b1, hb, N, E, 0, stats_sum, stats_sq, rowsum, maxkey);
    hipLaunchKernelGGL(fold_kernel, dim3(1), dim3(64), 0, stream, stats_sum, stats_sq, g1, be1, W2, Wf, cf, N);

    // ---- layer 2 ----
    hipLaunchKernelGGL(gemmf_kernel, dim3(gN), dim3(256), 0, stream, hb, Wf, cf, dinv, zb, N);
    hipLaunchKernelGGL(agg_kernel, dim3(AGG_BLOCKS), dim3(256), 0, stream, zb, csr_src, csr_off,
                       dinv, b2, hb, N, E, 0, stats_sum, stats_sq, rowsum, maxkey);
    hipLaunchKernelGGL(fold_kernel, dim3(1), dim3(64), 0, stream, stats_sum, stats_sq, g2, be2, W3, Wf, cf, N);

    // ---- layer 3 ----
    hipLaunchKernelGGL(gemmf_kernel, dim3(gN), dim3(256), 0, stream, hb, Wf, cf, dinv, zb, N);
    hipLaunchKernelGGL(agg_kernel, dim3(AGG_BLOCKS), dim3(256), 0, stream, zb, csr_src, csr_off,
                       dinv, b3, hb, N, E, 1, stats_sum, stats_sq, rowsum, maxkey);

    // ---- pooling + heads ----
    hipLaunchKernelGGL(pool_kernel, dim3(AGG_BLOCKS), dim3(256), 0, stream, hb, rowsum, maxkey, gvec, Zp, N);
    hipLaunchKernelGGL(dn_kernel, dim3(1), dim3(64), 0, stream, gvec, Zp, Wd1, bd1, Wd2, bd2, out, C);
    hipLaunchKernelGGL(cand_kernel, dim3(gN), dim3(256), 0, stream, hb, nt, cand_pos,
                       Wc1, bc1, Wc2, bc2, out, N, C);
}

// Round 5
// 562.974 us; speedup vs baseline: 1.3084x; 1.3084x over previous
//
#include <hip/hip_runtime.h>
#include <hip/hip_bf16.h>

typedef unsigned int uint;
typedef unsigned short ushort;

// bf16 bit-level conversions (RNE pack, exact unpack) for internal z/h storage
static __device__ __forceinline__ ushort f2b(float f) {
    uint u = __float_as_uint(f);
    uint r = (u + 0x7FFFu + ((u >> 16) & 1u)) >> 16;
    return (ushort)r;
}
static __device__ __forceinline__ float b2f_u(ushort h) { return __uint_as_float(((uint)h) << 16); }

static __device__ __forceinline__ void unpack8(uint4 v, float* o) {
    o[0] = b2f_u(v.x & 0xFFFF); o[1] = b2f_u(v.x >> 16);
    o[2] = b2f_u(v.y & 0xFFFF); o[3] = b2f_u(v.y >> 16);
    o[4] = b2f_u(v.z & 0xFFFF); o[5] = b2f_u(v.z >> 16);
    o[6] = b2f_u(v.w & 0xFFFF); o[7] = b2f_u(v.w >> 16);
}

// ---------------- wave-level inclusive scan (64 lanes) ----------------
static __device__ __forceinline__ unsigned wave_incl_scan(unsigned v) {
    int lane = threadIdx.x & 63;
    #pragma unroll
    for (int d = 1; d < 64; d <<= 1) {
        unsigned t = (unsigned)__shfl_up((int)v, d, 64);
        if (lane >= d) v += t;
    }
    return v;
}

// ---------------- dual scan pass 1: deg-scan (+dinv) and cand-scan ----------------
__global__ __launch_bounds__(1024) void scanA_kernel(const unsigned* deg, const int* nt,
                                                     unsigned* csr_off, unsigned* cand_pos,
                                                     float* dinv, unsigned* blocksum, int n) {
    __shared__ unsigned wsumA[16], wsumB[16];
    int idx = blockIdx.x * 1024 + threadIdx.x;
    unsigned a = 0, b = 0;
    if (idx < n) {
        unsigned d = deg[idx];
        a = d;
        dinv[idx] = rsqrtf((float)(d + 1u));   // +1 self loop
        b = (nt[idx] == 0) ? 1u : 0u;
    }
    unsigned ia = wave_incl_scan(a);
    unsigned ib = wave_incl_scan(b);
    int wid = threadIdx.x >> 6, lane = threadIdx.x & 63;
    if (lane == 63) { wsumA[wid] = ia; wsumB[wid] = ib; }
    __syncthreads();
    if (threadIdx.x < 64) {
        unsigned wa = (threadIdx.x < 16) ? wsumA[threadIdx.x] : 0u;
        unsigned wb = (threadIdx.x < 16) ? wsumB[threadIdx.x] : 0u;
        unsigned sa = wave_incl_scan(wa);
        unsigned sb = wave_incl_scan(wb);
        if (threadIdx.x < 16) { wsumA[threadIdx.x] = sa - wa; wsumB[threadIdx.x] = sb - wb; }
    }
    __syncthreads();
    unsigned ea = ia - a + wsumA[wid];
    unsigned eb = ib - b + wsumB[wid];
    if (idx < n) { csr_off[idx] = ea; cand_pos[idx] = eb; }
    if (threadIdx.x == 1023) { blocksum[blockIdx.x] = ea + a; blocksum[1024 + blockIdx.x] = eb + b; }
}

__global__ __launch_bounds__(1024) void scan2_kernel(const unsigned* blocksum, unsigned* blockoff, int nb) {
    __shared__ unsigned wsum[16];
    for (int part = 0; part < 2; part++) {
        int t = threadIdx.x;
        unsigned v = (t < nb) ? blocksum[part * 1024 + t] : 0u;
        unsigned incl = wave_incl_scan(v);
        int wid = t >> 6, lane = t & 63;
        if (lane == 63) wsum[wid] = incl;
        __syncthreads();
        if (t < 64) {
            unsigned wv = (t < 16) ? wsum[t] : 0u;
            unsigned ws = wave_incl_scan(wv);
            if (t < 16) wsum[t] = ws - wv;
        }
        __syncthreads();
        if (t < nb) blockoff[part * 1024 + t] = incl - v + wsum[wid];
        __syncthreads();
    }
}

__global__ void scan3_kernel(unsigned* csr_off, unsigned* cand_pos, const unsigned* blockoff, int n) {
    int idx = blockIdx.x * blockDim.x + threadIdx.x;
    if (idx < n) {
        csr_off[idx]  += blockoff[idx >> 10];
        cand_pos[idx] += blockoff[1024 + (idx >> 10)];
    }
}

// ---------------- CSR build ----------------
__global__ void hist_kernel(const int* dst, unsigned* deg, int E, int N) {
    int e = blockIdx.x * 256 + threadIdx.x;
    if (e < E) {
        int d = dst[e];
        if ((unsigned)d < (unsigned)N) atomicAdd(&deg[d], 1u);
    }
}

__global__ void fill_kernel(const int* src, const int* dst, const unsigned* off, unsigned* cnt,
                            int* csr_src, int E, int N) {
    int e = blockIdx.x * 256 + threadIdx.x;
    if (e < E) {
        int s = src[e];
        int d = dst[e];
        if ((unsigned)d < (unsigned)N && (unsigned)s < (unsigned)N) {
            unsigned p = off[d] + atomicAdd(&cnt[d], 1u);
            if (p < (unsigned)E) csr_src[p] = s;
        }
    }
}

// ---------------- layer-1 GEMM: z = (x @ W1) * dinv[row], bf16 out ----------------
__global__ __launch_bounds__(256) void gemm1_kernel(const float* x, const float* W1,
                                                    const float* dinv, ushort* zb, int n) {
    __shared__ float Ws[96];
    if (threadIdx.x < 96) Ws[threadIdx.x] = W1[threadIdx.x];
    __syncthreads();
    int i = blockIdx.x * 256 + threadIdx.x;
    if (i >= n) return;
    float x0 = x[i * 3], x1 = x[i * 3 + 1], x2 = x[i * 3 + 2];
    float di = dinv[i];
    uint pk[16];
    #pragma unroll
    for (int q = 0; q < 16; q++) {
        int j0 = 2 * q, j1 = 2 * q + 1;
        float o0 = (x0 * Ws[j0] + x1 * Ws[32 + j0] + x2 * Ws[64 + j0]) * di;
        float o1 = (x0 * Ws[j1] + x1 * Ws[32 + j1] + x2 * Ws[64 + j1]) * di;
        pk[q] = (uint)f2b(o0) | ((uint)f2b(o1) << 16);
    }
    uint4* zp = (uint4*)(zb + (size_t)i * 32);
    #pragma unroll
    for (int r = 0; r < 4; r++) zp[r] = make_uint4(pk[4*r], pk[4*r+1], pk[4*r+2], pk[4*r+3]);
}

// ---------------- folded GEMM with inline BN fold ----------------
// z = (bn(h) @ W + 0)*dinv  where bn folds as h*a + d;  Ws = diag(a)W, cs = d@W
__global__ __launch_bounds__(256) void gemmf_kernel(const ushort* hb, const float* stats_sum,
                                                    const float* stats_sq, const float* g,
                                                    const float* be, const float* W,
                                                    const float* dinv, ushort* zb, int n,
                                                    float inv_n) {
    __shared__ float Ws[1024];
    __shared__ float cs[32];
    __shared__ float a_s[32], d_s[32];
    int tid = threadIdx.x;
    if (tid < 32) {
        float mu = stats_sum[tid] * inv_n;
        float var = fmaxf(stats_sq[tid] * inv_n - mu * mu, 0.f);
        float a = g[tid] * rsqrtf(var + 1e-5f);
        a_s[tid] = a;
        d_s[tid] = be[tid] - mu * a;
    }
    __syncthreads();
    #pragma unroll
    for (int t = tid; t < 1024; t += 256) Ws[t] = a_s[t >> 5] * W[t];
    if (tid < 32) {
        float c = 0.f;
        for (int k = 0; k < 32; k++) c += d_s[k] * W[k * 32 + tid];
        cs[tid] = c;
    }
    __syncthreads();
    int i = blockIdx.x * 256 + tid;
    if (i >= n) return;
    const uint4* hp = (const uint4*)(hb + (size_t)i * 32);
    float hk[32];
    #pragma unroll
    for (int r = 0; r < 4; r++) unpack8(hp[r], hk + r * 8);
    float acc[32];
    #pragma unroll
    for (int j = 0; j < 32; j++) acc[j] = cs[j];
    #pragma unroll
    for (int k = 0; k < 32; k++) {
        float h0 = hk[k];
        #pragma unroll
        for (int j = 0; j < 32; j++) acc[j] += h0 * Ws[k * 32 + j];
    }
    float di = dinv[i];
    uint pk[16];
    #pragma unroll
    for (int q = 0; q < 16; q++)
        pk[q] = (uint)f2b(acc[2*q] * di) | ((uint)f2b(acc[2*q+1] * di) << 16);
    uint4* zp = (uint4*)(zb + (size_t)i * 32);
    #pragma unroll
    for (int r = 0; r < 4; r++) zp[r] = make_uint4(pk[4*r], pk[4*r+1], pk[4*r+2], pk[4*r+3]);
}

// ---------------- aggregate: one node per 64-lane wave, uint4 gathers ----------------
// lane layout: c4 = lane&3 (channels c4*8..c4*8+7), g = lane>>2 (row group 0..15)
__global__ __launch_bounds__(256) void agg_kernel(const ushort* zb, const int* csr_src,
                                                  const unsigned* off, const float* dinv,
                                                  const float* bias, ushort* hb, int n, int E,
                                                  int mode, float* stats_sum, float* stats_sq,
                                                  float* rowsum, unsigned* maxkey) {
    const int tid = threadIdx.x;
    const int wave = tid >> 6;
    const int lane = tid & 63;
    const int c4 = lane & 3;
    const int g  = lane >> 2;
    float bv[8];
    #pragma unroll
    for (int j = 0; j < 8; j++) bv[j] = bias[c4 * 8 + j];
    float bs[8], bq[8];
    #pragma unroll
    for (int j = 0; j < 8; j++) { bs[j] = 0.f; bq[j] = 0.f; }
    float lmax = -3.0e38f;
    const int nwaves = gridDim.x * 4;
    for (int node = blockIdx.x * 4 + wave; node < n; node += nwaves) {
        unsigned s = off[node];
        unsigned e = (node + 1 < n) ? off[node + 1] : (unsigned)E;
        if (e > (unsigned)E) e = (unsigned)E;
        if (s > e) s = e;
        float acc[8];
        if (g == 0) {   // self loop
            uint4 v = *(const uint4*)(zb + (size_t)node * 32 + c4 * 8);
            unpack8(v, acc);
        } else {
            #pragma unroll
            for (int j = 0; j < 8; j++) acc[j] = 0.f;
        }
        for (unsigned p = s; p < e; p += 16) {
            unsigned idx = p + (unsigned)g;
            if (idx < e) {
                unsigned src = (unsigned)csr_src[idx];
                if (src < (unsigned)n) {
                    uint4 v = *(const uint4*)(zb + (size_t)src * 32 + c4 * 8);
                    float t[8];
                    unpack8(v, t);
                    #pragma unroll
                    for (int j = 0; j < 8; j++) acc[j] += t[j];
                }
            }
        }
        // reduce over row groups (lane bits 2..5)
        #pragma unroll
        for (int m = 4; m < 64; m <<= 1) {
            #pragma unroll
            for (int j = 0; j < 8; j++) acc[j] += __shfl_xor(acc[j], m, 64);
        }
        float di = dinv[node];
        float hv[8];
        #pragma unroll
        for (int j = 0; j < 8; j++) hv[j] = fmaxf(di * acc[j] + bv[j], 0.f);
        if (g == 0) {
            uint4 o;
            o.x = (uint)f2b(hv[0]) | ((uint)f2b(hv[1]) << 16);
            o.y = (uint)f2b(hv[2]) | ((uint)f2b(hv[3]) << 16);
            o.z = (uint)f2b(hv[4]) | ((uint)f2b(hv[5]) << 16);
            o.w = (uint)f2b(hv[6]) | ((uint)f2b(hv[7]) << 16);
            *(uint4*)(hb + (size_t)node * 32 + c4 * 8) = o;
        }
        if (mode == 0) {
            if (g == 0) {
                #pragma unroll
                for (int j = 0; j < 8; j++) { bs[j] += hv[j]; bq[j] += hv[j] * hv[j]; }
            }
        } else {
            float rs = ((hv[0] + hv[1]) + (hv[2] + hv[3])) + ((hv[4] + hv[5]) + (hv[6] + hv[7]));
            rs += __shfl_xor(rs, 1, 64);
            rs += __shfl_xor(rs, 2, 64);
            if (lane == 0) { rowsum[node] = rs; lmax = fmaxf(lmax, rs); }
        }
    }
    if (mode == 0) {
        __shared__ float ssum[4][32], ssq[4][32];
        if (g == 0) {
            #pragma unroll
            for (int j = 0; j < 8; j++) { ssum[wave][c4 * 8 + j] = bs[j]; ssq[wave][c4 * 8 + j] = bq[j]; }
        }
        __syncthreads();
        if (tid < 32) {
            float a = ssum[0][tid] + ssum[1][tid] + ssum[2][tid] + ssum[3][tid];
            float b = ssq[0][tid] + ssq[1][tid] + ssq[2][tid] + ssq[3][tid];
            atomicAdd(&stats_sum[tid], a);
            atomicAdd(&stats_sq[tid], b);
        }
    } else {
        __shared__ float lm[4];
        if (lane == 0) lm[wave] = lmax;
        __syncthreads();
        if (tid == 0) {
            float m = fmaxf(fmaxf(lm[0], lm[1]), fmaxf(lm[2], lm[3]));
            unsigned u = __float_as_uint(m);
            unsigned key = (u & 0x80000000u) ? ~u : (u | 0x80000000u);
            atomicMax(maxkey, key);
        }
    }
}

// ---------------- softmax-weighted pooling ----------------
__global__ __launch_bounds__(256) void pool_kernel(const ushort* hb, const float* rowsum,
                                                   const unsigned* maxkey, float* gvec, float* Zp,
                                                   int n) {
    unsigned key = *maxkey;
    float M = 0.f;
    if (key != 0u) M = (key & 0x80000000u) ? __uint_as_float(key ^ 0x80000000u) : __uint_as_float(~key);
    int lane = threadIdx.x & 31;
    int grp = threadIdx.x >> 5;
    int stride = gridDim.x * 8;
    float accZ = 0.f, accg = 0.f;
    for (int node = blockIdx.x * 8 + grp; node < n; node += stride) {
        float e = __expf(rowsum[node] - M);
        accg += b2f_u(hb[(size_t)node * 32 + lane]) * e;
        if (lane == 0) accZ += e;
    }
    __shared__ float ls[256];
    ls[threadIdx.x] = accg;
    __syncthreads();
    if (threadIdx.x < 32) {
        float a = 0.f;
        #pragma unroll
        for (int g = 0; g < 8; g++) a += ls[threadIdx.x + 32 * g];
        atomicAdd(&gvec[threadIdx.x], a);
    }
    __syncthreads();
    ls[threadIdx.x] = (lane == 0) ? accZ : 0.f;
    __syncthreads();
    if (threadIdx.x == 0) {
        float a = 0.f;
        for (int t = 0; t < 256; t += 32) a += ls[t];
        atomicAdd(Zp, a);
    }
}

// ---------------- candidate head (+ fused graph head in block 0) ----------------
__global__ __launch_bounds__(256) void cand_kernel(const ushort* hb, const int* nt,
                                                   const unsigned* pos, const float* Wc1,
                                                   const float* bc1, const float* Wc2,
                                                   const float* bc2, const float* gvec,
                                                   const float* Zp, const float* Wd1,
                                                   const float* bd1, const float* Wd2,
                                                   const float* bd2, float* out, int n, int C) {
    __shared__ float W1s[512], b1s[16], W2s[16];
    for (int t = threadIdx.x; t < 512; t += 256) W1s[t] = Wc1[t];
    if (threadIdx.x < 16) { b1s[threadIdx.x] = bc1[threadIdx.x]; W2s[threadIdx.x] = Wc2[threadIdx.x]; }
    __syncthreads();
    int i = blockIdx.x * 256 + threadIdx.x;
    if (i < n && nt[i] == 0) {
        const uint4* hp = (const uint4*)(hb + (size_t)i * 32);
        float hv[32];
        #pragma unroll
        for (int r = 0; r < 4; r++) unpack8(hp[r], hv + r * 8);
        float s = bc2[0];
        #pragma unroll
        for (int j = 0; j < 16; j++) {
            float u = b1s[j];
            #pragma unroll
            for (int k = 0; k < 32; k++) u += hv[k] * W1s[k * 16 + j];
            s += fmaxf(u, 0.f) * W2s[j];
        }
        s = fminf(fmaxf(s, -1000.f), 1000.f);
        unsigned p = pos[i];
        if (p < (unsigned)C) {
            out[p] = s;
            out[C + 1 + p] = (float)i;
        }
    }
    if (blockIdx.x == 0) {
        __shared__ float ge[32], tt[16];
        int t = threadIdx.x;
        __syncthreads();
        if (t < 32) ge[t] = gvec[t] / fmaxf(*Zp, 1e-30f);
        __syncthreads();
        if (t < 16) {
            float s = bd1[t];
            for (int k = 0; k < 32; k++) s += ge[k] * Wd1[k * 16 + t];
            tt[t] = fmaxf(s, 0.f);
        }
        __syncthreads();
        if (t == 0) {
            float s = bd2[0];
            for (int j = 0; j < 16; j++) s += tt[j] * Wd2[j];
            out[C] = fminf(fmaxf(s, -1000.f), 1000.f);
        }
    }
}

// ---------------- host launch ----------------
extern "C" void kernel_launch(void* const* d_in, const int* in_sizes, int n_in,
                              void* d_out, int out_size, void* d_ws, size_t ws_size,
                              hipStream_t stream) {
    const float* x   = (const float*)d_in[0];
    const int*   ei  = (const int*)d_in[1];
    const int*   nt  = (const int*)d_in[2];
    const float* W1  = (const float*)d_in[3];  const float* b1  = (const float*)d_in[4];
    const float* W2  = (const float*)d_in[5];  const float* b2  = (const float*)d_in[6];
    const float* W3  = (const float*)d_in[7];  const float* b3  = (const float*)d_in[8];
    const float* g1  = (const float*)d_in[9];  const float* be1 = (const float*)d_in[10];
    const float* g2  = (const float*)d_in[11]; const float* be2 = (const float*)d_in[12];
    const float* Wc1 = (const float*)d_in[13]; const float* bc1 = (const float*)d_in[14];
    const float* Wc2 = (const float*)d_in[15]; const float* bc2 = (const float*)d_in[16];
    const float* Wd1 = (const float*)d_in[17]; const float* bd1 = (const float*)d_in[18];
    const float* Wd2 = (const float*)d_in[19]; const float* bd2 = (const float*)d_in[20];

    const int N = in_sizes[0] / 3;
    const int E = in_sizes[1] / 2;
    const int C = (out_size - 1) / 2;
    const int* e_src = ei;
    const int* e_dst = ei + E;
    float* out = (float*)d_out;

    // ---- workspace: stats/deg/cnt FIRST (one contiguous zeroed region) ----
    char* w = (char*)d_ws;
    auto alloc = [&](size_t bytes) { void* p = (void*)w; w += (bytes + 255) & ~(size_t)255; return p; };
    float*    stats    = (float*)alloc(256 * 4);
    unsigned* deg      = (unsigned*)alloc((size_t)N * 4);
    unsigned* cnt      = (unsigned*)alloc((size_t)N * 4);   // reused as rowsum after fill
    size_t zero_bytes  = (size_t)((char*)w - (char*)stats);
    unsigned* blocksum = (unsigned*)alloc(2048 * 4);
    unsigned* blockoff = (unsigned*)alloc(2048 * 4);
    float*    dinv     = (float*)alloc((size_t)N * 4);
    unsigned* csr_off  = (unsigned*)alloc((size_t)N * 4);
    unsigned* cand_pos = (unsigned*)alloc((size_t)N * 4);
    int*      csr_src  = (int*)alloc((size_t)E * 4);
    ushort*   zb       = (ushort*)alloc((size_t)N * 32 * 2);
    ushort*   hb       = (ushort*)alloc((size_t)N * 32 * 2);

    float* sum1   = stats;          // layer-1 BN stats
    float* sq1    = stats + 32;
    float* sum2   = stats + 64;     // layer-2 BN stats
    float* sq2    = stats + 96;
    float* gvec   = stats + 128;
    float* Zp     = stats + 160;
    unsigned* maxkey = (unsigned*)(stats + 161);
    float* rowsum = (float*)cnt;

    hipMemsetAsync(stats, 0, zero_bytes, stream);

    const int nb1 = (N + 1023) / 1024;
    const int gN  = (N + 255) / 256;
    const int gE  = (E + 255) / 256;
    const float inv_n = 1.0f / (float)N;

    // ---- CSR build + scans ----
    hipLaunchKernelGGL(hist_kernel, dim3(gE), dim3(256), 0, stream, e_dst, deg, E, N);
    hipLaunchKernelGGL(scanA_kernel, dim3(nb1), dim3(1024), 0, stream, deg, nt, csr_off, cand_pos, dinv, blocksum, N);
    hipLaunchKernelGGL(scan2_kernel, dim3(1), dim3(1024), 0, stream, blocksum, blockoff, nb1);
    hipLaunchKernelGGL(scan3_kernel, dim3(gN), dim3(256), 0, stream, csr_off, cand_pos, blockoff, N);
    hipLaunchKernelGGL(fill_kernel, dim3(gE), dim3(256), 0, stream, e_src, e_dst, csr_off, cnt, csr_src, E, N);

    const int AGG_BLOCKS = 2048;

    // ---- layer 1 ----
    hipLaunchKernelGGL(gemm1_kernel, dim3(gN), dim3(256), 0, stream, x, W1, dinv, zb, N);
    hipLaunchKernelGGL(agg_kernel, dim3(AGG_BLOCKS), dim3(256), 0, stream, zb, csr_src, csr_off,
                       dinv, b1, hb, N, E, 0, sum1, sq1, rowsum, maxkey);

    // ---- layer 2 (fold of BN1 inlined) ----
    hipLaunchKernelGGL(gemmf_kernel, dim3(gN), dim3(256), 0, stream, hb, sum1, sq1, g1, be1, W2,
                       dinv, zb, N, inv_n);
    hipLaunchKernelGGL(agg_kernel, dim3(AGG_BLOCKS), dim3(256), 0, stream, zb, csr_src, csr_off,
                       dinv, b2, hb, N, E, 0, sum2, sq2, rowsum, maxkey);

    // ---- layer 3 (fold of BN2 inlined; no BN after) ----
    hipLaunchKernelGGL(gemmf_kernel, dim3(gN), dim3(256), 0, stream, hb, sum2, sq2, g2, be2, W3,
                       dinv, zb, N, inv_n);
    hipLaunchKernelGGL(agg_kernel, dim3(AGG_BLOCKS), dim3(256), 0, stream, zb, csr_src, csr_off,
                       dinv, b3, hb, N, E, 1, sum1, sq1, rowsum, maxkey);

    // ---- pooling + heads ----
    hipLaunchKernelGGL(pool_kernel, dim3(1024), dim3(256), 0, stream, hb, rowsum, maxkey, gvec, Zp, N);
    hipLaunchKernelGGL(cand_kernel, dim3(gN), dim3(256), 0, stream, hb, nt, cand_pos,
                       Wc1, bc1, Wc2, bc2, gvec, Zp, Wd1, bd1, Wd2, bd2, out, N, C);
}

// Round 6
// 399.523 us; speedup vs baseline: 1.8437x; 1.4091x over previous
//
#include <hip/hip_runtime.h>
#include <hip/hip_bf16.h>

typedef unsigned int uint;
typedef unsigned short ushort;

#define NB_MAX 256      // max buckets
#define NPB_MAX 2048    // max nodes per bucket

// bf16 bit-level conversions (RNE pack, exact unpack) for internal z/h storage
static __device__ __forceinline__ ushort f2b(float f) {
    uint u = __float_as_uint(f);
    uint r = (u + 0x7FFFu + ((u >> 16) & 1u)) >> 16;
    return (ushort)r;
}
static __device__ __forceinline__ float b2f_u(ushort h) { return __uint_as_float(((uint)h) << 16); }

static __device__ __forceinline__ void unpack8(uint4 v, float* o) {
    o[0] = b2f_u(v.x & 0xFFFF); o[1] = b2f_u(v.x >> 16);
    o[2] = b2f_u(v.y & 0xFFFF); o[3] = b2f_u(v.y >> 16);
    o[4] = b2f_u(v.z & 0xFFFF); o[5] = b2f_u(v.z >> 16);
    o[6] = b2f_u(v.w & 0xFFFF); o[7] = b2f_u(v.w >> 16);
}

// ---------------- wave-level inclusive scan (64 lanes) ----------------
static __device__ __forceinline__ unsigned wave_incl_scan(unsigned v) {
    int lane = threadIdx.x & 63;
    #pragma unroll
    for (int d = 1; d < 64; d <<= 1) {
        unsigned t = (unsigned)__shfl_up((int)v, d, 64);
        if (lane >= d) v += t;
    }
    return v;
}

// exclusive block scan: in[0..n) -> out[0..n), n <= 2048, 256 threads, wscr = shared[4]
static __device__ void block_excl_scan(const uint* in, uint* out, int n, uint* wscr) {
    int tid = threadIdx.x;
    int lane = tid & 63, wid = tid >> 6;
    int base = tid * 8;
    uint v[8], pre[8], s = 0;
    #pragma unroll
    for (int k = 0; k < 8; k++) v[k] = (base + k < n) ? in[base + k] : 0u;
    #pragma unroll
    for (int k = 0; k < 8; k++) { pre[k] = s; s += v[k]; }
    uint is = wave_incl_scan(s);
    __syncthreads();                 // protect wscr from previous use
    if (lane == 63) wscr[wid] = is;
    __syncthreads();
    uint woff = 0;
    for (int wI = 0; wI < wid; wI++) woff += wscr[wI];
    uint excl = is - s + woff;
    #pragma unroll
    for (int k = 0; k < 8; k++) if (base + k < n) out[base + k] = excl + pre[k];
    __syncthreads();
}

// ---------------- phase 1: per-bucket edge & candidate histograms ----------------
__global__ __launch_bounds__(256) void bucket_hist_kernel(const int* src, const int* dst,
                                                          const int* nt, uint* bcnt, uint* bcand,
                                                          int E, int N, int NB, int shift) {
    __shared__ uint bh[NB_MAX], ch[NB_MAX];
    int tid = threadIdx.x;
    for (int i = tid; i < NB_MAX; i += 256) { bh[i] = 0; ch[i] = 0; }
    __syncthreads();
    int gs = gridDim.x * 256;
    for (int i = blockIdx.x * 256 + tid; i < E; i += gs) {
        int d = dst[i], s = src[i];
        if ((uint)d < (uint)N && (uint)s < (uint)N) atomicAdd(&bh[d >> shift], 1u);
    }
    for (int i = blockIdx.x * 256 + tid; i < N; i += gs) {
        if (nt[i] == 0) atomicAdd(&ch[i >> shift], 1u);
    }
    __syncthreads();
    for (int i = tid; i < NB; i += 256) {
        if (bh[i]) atomicAdd(&bcnt[i], bh[i]);
        if (ch[i]) atomicAdd(&bcand[i], ch[i]);
    }
}

// ---------------- phase 2: scan bucket counters (1 block) ----------------
__global__ __launch_bounds__(256) void bucket_scan_kernel(const uint* bcnt, const uint* bcand,
                                                          uint* bbase, uint* cbase, uint* balloc,
                                                          int NB) {
    __shared__ uint wsA[4], wsB[4];
    int t = threadIdx.x;
    int lane = t & 63, wid = t >> 6;
    uint a = (t < NB) ? bcnt[t] : 0u;
    uint c = (t < NB) ? bcand[t] : 0u;
    uint ia = wave_incl_scan(a);
    uint ic = wave_incl_scan(c);
    if (lane == 63) { wsA[wid] = ia; wsB[wid] = ic; }
    __syncthreads();
    uint offA = 0, offC = 0;
    for (int wI = 0; wI < wid; wI++) { offA += wsA[wI]; offC += wsB[wI]; }
    uint ea = ia - a + offA, ec = ic - c + offC;
    if (t < NB) { bbase[t] = ea; cbase[t] = ec; balloc[t] = ea; }
    if (t == NB - 1) { bbase[NB] = ea + a; cbase[NB] = ec + c; }
}

// ---------------- phase 3: partition edges into bucket-contiguous staging ----------------
__global__ __launch_bounds__(256) void partition_kernel(const int* src, const int* dst,
                                                        uint* balloc, uint2* staging,
                                                        int E, int N, int shift) {
    __shared__ uint lh[NB_MAX];
    __shared__ uint gb[NB_MAX];
    int tid = threadIdx.x;
    for (int i = tid; i < NB_MAX; i += 256) lh[i] = 0;
    __syncthreads();
    int base = blockIdx.x * 2048;
    int sreg[8], dreg[8], breg[8];
    uint rreg[8];
    #pragma unroll
    for (int k = 0; k < 8; k++) {
        int e = base + k * 256 + tid;
        breg[k] = -1;
        if (e < E) {
            int s = src[e], d = dst[e];
            if ((uint)d < (uint)N && (uint)s < (uint)N) {
                int b = d >> shift;
                sreg[k] = s; dreg[k] = d; breg[k] = b;
                rreg[k] = atomicAdd(&lh[b], 1u);
            }
        }
    }
    __syncthreads();
    for (int i = tid; i < NB_MAX; i += 256)
        gb[i] = lh[i] ? atomicAdd(&balloc[i], lh[i]) : 0u;
    __syncthreads();
    #pragma unroll
    for (int k = 0; k < 8; k++) {
        if (breg[k] >= 0)
            staging[gb[breg[k]] + rreg[k]] = make_uint2((uint)sreg[k], (uint)dreg[k]);
    }
}

// ---------------- phase 4: per-bucket local counting sort + csr_off/dinv/cand_pos ----------------
__global__ __launch_bounds__(256) void local_csr_kernel(const uint2* staging, const uint* bbase,
                                                        const uint* cbase, const int* nt,
                                                        int* csr_src, uint* csr_off, uint* cand_pos,
                                                        float* dinv, int N, int shift, int NB) {
    __shared__ uint deg[NPB_MAX];
    __shared__ uint ofs[NPB_MAX];
    __shared__ uint wscr[4];
    int b = blockIdx.x;
    int tid = threadIdx.x;
    int nbase = b << shift;
    int nend = min(nbase + (1 << shift), N);
    int ncount = nend - nbase;
    uint ebase = bbase[b], eend = bbase[b + 1];
    for (int i = tid; i < ncount; i += 256) deg[i] = 0;
    __syncthreads();
    for (uint p = ebase + tid; p < eend; p += 256)
        atomicAdd(&deg[staging[p].y - (uint)nbase], 1u);
    __syncthreads();
    block_excl_scan(deg, ofs, ncount, wscr);
    for (int i = tid; i < ncount; i += 256) {
        csr_off[nbase + i] = ebase + ofs[i];
        dinv[nbase + i] = rsqrtf((float)(deg[i] + 1u));   // +1 self loop
    }
    if (b == NB - 1 && tid == 0) csr_off[N] = eend;
    __syncthreads();
    for (int i = tid; i < ncount; i += 256) deg[i] = 0;   // reuse as running counters
    __syncthreads();
    for (uint p = ebase + tid; p < eend; p += 256) {
        uint2 pr = staging[p];
        uint dl = pr.y - (uint)nbase;
        uint pos = ebase + ofs[dl] + atomicAdd(&deg[dl], 1u);
        csr_src[pos] = (int)pr.x;
    }
    __syncthreads();
    // candidate positions (bucket-local scan of indicator)
    for (int i = tid; i < ncount; i += 256) deg[i] = (nt[nbase + i] == 0) ? 1u : 0u;
    __syncthreads();
    block_excl_scan(deg, ofs, ncount, wscr);
    uint cb = cbase[b];
    for (int i = tid; i < ncount; i += 256) cand_pos[nbase + i] = cb + ofs[i];
}

// ---------------- layer-1 GEMM: z = (x @ W1) * dinv[row], bf16 out ----------------
__global__ __launch_bounds__(256) void gemm1_kernel(const float* x, const float* W1,
                                                    const float* dinv, ushort* zb, int n) {
    __shared__ float Ws[96];
    if (threadIdx.x < 96) Ws[threadIdx.x] = W1[threadIdx.x];
    __syncthreads();
    int i = blockIdx.x * 256 + threadIdx.x;
    if (i >= n) return;
    float x0 = x[i * 3], x1 = x[i * 3 + 1], x2 = x[i * 3 + 2];
    float di = dinv[i];
    uint pk[16];
    #pragma unroll
    for (int q = 0; q < 16; q++) {
        int j0 = 2 * q, j1 = 2 * q + 1;
        float o0 = (x0 * Ws[j0] + x1 * Ws[32 + j0] + x2 * Ws[64 + j0]) * di;
        float o1 = (x0 * Ws[j1] + x1 * Ws[32 + j1] + x2 * Ws[64 + j1]) * di;
        pk[q] = (uint)f2b(o0) | ((uint)f2b(o1) << 16);
    }
    uint4* zp = (uint4*)(zb + (size_t)i * 32);
    #pragma unroll
    for (int r = 0; r < 4; r++) zp[r] = make_uint4(pk[4*r], pk[4*r+1], pk[4*r+2], pk[4*r+3]);
}

// ---------------- folded GEMM with inline BN fold ----------------
__global__ __launch_bounds__(256) void gemmf_kernel(const ushort* hb, const float* stats_sum,
                                                    const float* stats_sq, const float* g,
                                                    const float* be, const float* W,
                                                    const float* dinv, ushort* zb, int n,
                                                    float inv_n) {
    __shared__ float Ws[1024];
    __shared__ float cs[32];
    __shared__ float a_s[32], d_s[32];
    int tid = threadIdx.x;
    if (tid < 32) {
        float mu = stats_sum[tid] * inv_n;
        float var = fmaxf(stats_sq[tid] * inv_n - mu * mu, 0.f);
        float a = g[tid] * rsqrtf(var + 1e-5f);
        a_s[tid] = a;
        d_s[tid] = be[tid] - mu * a;
    }
    __syncthreads();
    #pragma unroll
    for (int t = tid; t < 1024; t += 256) Ws[t] = a_s[t >> 5] * W[t];
    if (tid < 32) {
        float c = 0.f;
        for (int k = 0; k < 32; k++) c += d_s[k] * W[k * 32 + tid];
        cs[tid] = c;
    }
    __syncthreads();
    int i = blockIdx.x * 256 + tid;
    if (i >= n) return;
    const uint4* hp = (const uint4*)(hb + (size_t)i * 32);
    float hk[32];
    #pragma unroll
    for (int r = 0; r < 4; r++) unpack8(hp[r], hk + r * 8);
    float acc[32];
    #pragma unroll
    for (int j = 0; j < 32; j++) acc[j] = cs[j];
    #pragma unroll
    for (int k = 0; k < 32; k++) {
        float h0 = hk[k];
        #pragma unroll
        for (int j = 0; j < 32; j++) acc[j] += h0 * Ws[k * 32 + j];
    }
    float di = dinv[i];
    uint pk[16];
    #pragma unroll
    for (int q = 0; q < 16; q++)
        pk[q] = (uint)f2b(acc[2*q] * di) | ((uint)f2b(acc[2*q+1] * di) << 16);
    uint4* zp = (uint4*)(zb + (size_t)i * 32);
    #pragma unroll
    for (int r = 0; r < 4; r++) zp[r] = make_uint4(pk[4*r], pk[4*r+1], pk[4*r+2], pk[4*r+3]);
}

// ---------------- aggregate: one node per 4-lane quad ----------------
// lane: c4 = lane&3 (channel quad, 8 ch), slot = lane>>2 (node within wave, 16 nodes/wave)
__global__ __launch_bounds__(256) void agg_kernel(const ushort* zb, const int* csr_src,
                                                  const uint* csr_off, const float* dinv,
                                                  const float* bias, ushort* hb, int n,
                                                  int mode, float* stats_sum, float* stats_sq,
                                                  float* rowsum, uint* maxkey) {
    const int tid = threadIdx.x;
    const int wave = tid >> 6;
    const int lane = tid & 63;
    const int c4 = lane & 3;
    const int slot = lane >> 2;
    float bs[8], bq[8];
    #pragma unroll
    for (int j = 0; j < 8; j++) { bs[j] = 0.f; bq[j] = 0.f; }
    float lmax = -3.0e38f;
    int node = (blockIdx.x * 4 + wave) * 16 + slot;
    if (node < n) {
        uint s = csr_off[node], e = csr_off[node + 1];
        float acc[8];
        uint4 v = *(const uint4*)(zb + (size_t)node * 32 + c4 * 8);
        unpack8(v, acc);                                 // self loop
        for (uint p = s; p < e; ++p) {
            uint srcn = (uint)csr_src[p];
            if (srcn < (uint)n) {
                uint4 vv = *(const uint4*)(zb + (size_t)srcn * 32 + c4 * 8);
                float t[8];
                unpack8(vv, t);
                #pragma unroll
                for (int j = 0; j < 8; j++) acc[j] += t[j];
            }
        }
        float di = dinv[node];
        float bv[8];
        #pragma unroll
        for (int j = 0; j < 8; j++) bv[j] = bias[c4 * 8 + j];
        float hv[8];
        #pragma unroll
        for (int j = 0; j < 8; j++) hv[j] = fmaxf(di * acc[j] + bv[j], 0.f);
        uint4 o;
        o.x = (uint)f2b(hv[0]) | ((uint)f2b(hv[1]) << 16);
        o.y = (uint)f2b(hv[2]) | ((uint)f2b(hv[3]) << 16);
        o.z = (uint)f2b(hv[4]) | ((uint)f2b(hv[5]) << 16);
        o.w = (uint)f2b(hv[6]) | ((uint)f2b(hv[7]) << 16);
        *(uint4*)(hb + (size_t)node * 32 + c4 * 8) = o;
        if (mode == 0) {
            #pragma unroll
            for (int j = 0; j < 8; j++) { bs[j] = hv[j]; bq[j] = hv[j] * hv[j]; }
        } else {
            float rs = ((hv[0] + hv[1]) + (hv[2] + hv[3])) + ((hv[4] + hv[5]) + (hv[6] + hv[7]));
            rs += __shfl_xor(rs, 1, 64);
            rs += __shfl_xor(rs, 2, 64);
            if (c4 == 0) { rowsum[node] = rs; lmax = rs; }
        }
    }
    if (mode == 0) {
        #pragma unroll
        for (int m = 4; m < 64; m <<= 1) {
            #pragma unroll
            for (int j = 0; j < 8; j++) {
                bs[j] += __shfl_xor(bs[j], m, 64);
                bq[j] += __shfl_xor(bq[j], m, 64);
            }
        }
        __shared__ float ssum[4][32], ssq[4][32];
        if (slot == 0) {
            #pragma unroll
            for (int j = 0; j < 8; j++) { ssum[wave][c4 * 8 + j] = bs[j]; ssq[wave][c4 * 8 + j] = bq[j]; }
        }
        __syncthreads();
        if (tid < 32) {
            atomicAdd(&stats_sum[tid], ssum[0][tid] + ssum[1][tid] + ssum[2][tid] + ssum[3][tid]);
            atomicAdd(&stats_sq[tid],  ssq[0][tid] + ssq[1][tid] + ssq[2][tid] + ssq[3][tid]);
        }
    } else {
        #pragma unroll
        for (int m = 1; m < 64; m <<= 1) lmax = fmaxf(lmax, __shfl_xor(lmax, m, 64));
        __shared__ float lm[4];
        if (lane == 0) lm[wave] = lmax;
        __syncthreads();
        if (tid == 0) {
            float m = fmaxf(fmaxf(lm[0], lm[1]), fmaxf(lm[2], lm[3]));
            uint u = __float_as_uint(m);
            uint key = (u & 0x80000000u) ? ~u : (u | 0x80000000u);
            atomicMax(maxkey, key);
        }
    }
}

// ---------------- softmax-weighted pooling ----------------
__global__ __launch_bounds__(256) void pool_kernel(const ushort* hb, const float* rowsum,
                                                   const uint* maxkey, float* gvec, float* Zp,
                                                   int n) {
    uint key = *maxkey;
    float M = 0.f;
    if (key != 0u) M = (key & 0x80000000u) ? __uint_as_float(key ^ 0x80000000u) : __uint_as_float(~key);
    int lane = threadIdx.x & 31;
    int grp = threadIdx.x >> 5;
    int stride = gridDim.x * 8;
    float accZ = 0.f, accg = 0.f;
    for (int node = blockIdx.x * 8 + grp; node < n; node += stride) {
        float e = __expf(rowsum[node] - M);
        accg += b2f_u(hb[(size_t)node * 32 + lane]) * e;
        if (lane == 0) accZ += e;
    }
    __shared__ float ls[256];
    ls[threadIdx.x] = accg;
    __syncthreads();
    if (threadIdx.x < 32) {
        float a = 0.f;
        #pragma unroll
        for (int g = 0; g < 8; g++) a += ls[threadIdx.x + 32 * g];
        atomicAdd(&gvec[threadIdx.x], a);
    }
    __syncthreads();
    ls[threadIdx.x] = (lane == 0) ? accZ : 0.f;
    __syncthreads();
    if (threadIdx.x == 0) {
        float a = 0.f;
        for (int t = 0; t < 256; t += 32) a += ls[t];
        atomicAdd(Zp, a);
    }
}

// ---------------- candidate head (+ fused graph head in block 0) ----------------
__global__ __launch_bounds__(256) void cand_kernel(const ushort* hb, const int* nt,
                                                   const uint* pos, const float* Wc1,
                                                   const float* bc1, const float* Wc2,
                                                   const float* bc2, const float* gvec,
                                                   const float* Zp, const float* Wd1,
                                                   const float* bd1, const float* Wd2,
                                                   const float* bd2, float* out, int n, int C) {
    __shared__ float W1s[512], b1s[16], W2s[16];
    for (int t = threadIdx.x; t < 512; t += 256) W1s[t] = Wc1[t];
    if (threadIdx.x < 16) { b1s[threadIdx.x] = bc1[threadIdx.x]; W2s[threadIdx.x] = Wc2[threadIdx.x]; }
    __syncthreads();
    int i = blockIdx.x * 256 + threadIdx.x;
    if (i < n && nt[i] == 0) {
        const uint4* hp = (const uint4*)(hb + (size_t)i * 32);
        float hv[32];
        #pragma unroll
        for (int r = 0; r < 4; r++) unpack8(hp[r], hv + r * 8);
        float s = bc2[0];
        #pragma unroll
        for (int j = 0; j < 16; j++) {
            float u = b1s[j];
            #pragma unroll
            for (int k = 0; k < 32; k++) u += hv[k] * W1s[k * 16 + j];
            s += fmaxf(u, 0.f) * W2s[j];
        }
        s = fminf(fmaxf(s, -1000.f), 1000.f);
        uint p = pos[i];
        if (p < (uint)C) {
            out[p] = s;
            out[C + 1 + p] = (float)i;
        }
    }
    if (blockIdx.x == 0) {
        __shared__ float ge[32], tt[16];
        int t = threadIdx.x;
        __syncthreads();
        if (t < 32) ge[t] = gvec[t] / fmaxf(*Zp, 1e-30f);
        __syncthreads();
        if (t < 16) {
            float s = bd1[t];
            for (int k = 0; k < 32; k++) s += ge[k] * Wd1[k * 16 + t];
            tt[t] = fmaxf(s, 0.f);
        }
        __syncthreads();
        if (t == 0) {
            float s = bd2[0];
            for (int j = 0; j < 16; j++) s += tt[j] * Wd2[j];
            out[C] = fminf(fmaxf(s, -1000.f), 1000.f);
        }
    }
}

// ---------------- host launch ----------------
extern "C" void kernel_launch(void* const* d_in, const int* in_sizes, int n_in,
                              void* d_out, int out_size, void* d_ws, size_t ws_size,
                              hipStream_t stream) {
    const float* x   = (const float*)d_in[0];
    const int*   ei  = (const int*)d_in[1];
    const int*   nt  = (const int*)d_in[2];
    const float* W1  = (const float*)d_in[3];  const float* b1  = (const float*)d_in[4];
    const float* W2  = (const float*)d_in[5];  const float* b2  = (const float*)d_in[6];
    const float* W3  = (const float*)d_in[7];  const float* b3  = (const float*)d_in[8];
    const float* g1  = (const float*)d_in[9];  const float* be1 = (const float*)d_in[10];
    const float* g2  = (const float*)d_in[11]; const float* be2 = (const float*)d_in[12];
    const float* Wc1 = (const float*)d_in[13]; const float* bc1 = (const float*)d_in[14];
    const float* Wc2 = (const float*)d_in[15]; const float* bc2 = (const float*)d_in[16];
    const float* Wd1 = (const float*)d_in[17]; const float* bd1 = (const float*)d_in[18];
    const float* Wd2 = (const float*)d_in[19]; const float* bd2 = (const float*)d_in[20];

    const int N = in_sizes[0] / 3;
    const int E = in_sizes[1] / 2;
    const int C = (out_size - 1) / 2;
    const int* e_src = ei;
    const int* e_dst = ei + E;
    float* out = (float*)d_out;

    // bucket geometry: nodes/bucket = 1<<shift, NB <= 256
    int shift = 9;
    while (((N + (1 << shift) - 1) >> shift) > NB_MAX) shift++;
    const int NB = (N + (1 << shift) - 1) >> shift;

    // ---- workspace carve-up ----
    char* w = (char*)d_ws;
    auto alloc = [&](size_t bytes) { void* p = (void*)w; w += (bytes + 255) & ~(size_t)255; return p; };
    float*    stats  = (float*)alloc(256 * 4);     // zeroed
    uint*     bcnt   = (uint*)alloc(NB_MAX * 4);   // zeroed
    uint*     bcand  = (uint*)alloc(NB_MAX * 4);   // zeroed
    size_t zero_bytes = (size_t)((char*)w - (char*)stats);
    uint*     bbase  = (uint*)alloc((NB_MAX + 1) * 4);
    uint*     cbase  = (uint*)alloc((NB_MAX + 1) * 4);
    uint*     balloc_= (uint*)alloc(NB_MAX * 4);
    float*    dinv   = (float*)alloc((size_t)N * 4);
    uint*     csr_off= (uint*)alloc((size_t)(N + 1) * 4);
    uint*     cand_pos=(uint*)alloc((size_t)N * 4);
    float*    rowsum = (float*)alloc((size_t)N * 4);
    int*      csr_src= (int*)alloc((size_t)E * 4);
    ushort*   zb     = (ushort*)alloc((size_t)N * 32 * 2);
    ushort*   hb     = (ushort*)alloc((size_t)N * 32 * 2);
    // staging pairs alias zb+hb (dead before gemm1 writes zb); need E*8 <= N*128
    uint2*    staging = (uint2*)zb;

    float* sum1 = stats;       float* sq1 = stats + 32;
    float* sum2 = stats + 64;  float* sq2 = stats + 96;
    float* gvec = stats + 128; float* Zp  = stats + 160;
    uint* maxkey = (uint*)(stats + 161);

    hipMemsetAsync(stats, 0, zero_bytes, stream);

    const int gN   = (N + 255) / 256;
    const int gPar = (E + 2047) / 2048;
    const int gAgg = (N + 63) / 64;
    const float inv_n = 1.0f / (float)N;

    // ---- CSR build (XCD-local two-phase counting sort) ----
    hipLaunchKernelGGL(bucket_hist_kernel, dim3(784), dim3(256), 0, stream, e_src, e_dst, nt, bcnt, bcand, E, N, NB, shift);
    hipLaunchKernelGGL(bucket_scan_kernel, dim3(1), dim3(256), 0, stream, bcnt, bcand, bbase, cbase, balloc_, NB);
    hipLaunchKernelGGL(partition_kernel, dim3(gPar), dim3(256), 0, stream, e_src, e_dst, balloc_, staging, E, N, shift);
    hipLaunchKernelGGL(local_csr_kernel, dim3(NB), dim3(256), 0, stream, staging, bbase, cbase, nt,
                       csr_src, csr_off, cand_pos, dinv, N, shift, NB);

    // ---- layer 1 ----
    hipLaunchKernelGGL(gemm1_kernel, dim3(gN), dim3(256), 0, stream, x, W1, dinv, zb, N);
    hipLaunchKernelGGL(agg_kernel, dim3(gAgg), dim3(256), 0, stream, zb, csr_src, csr_off,
                       dinv, b1, hb, N, 0, sum1, sq1, rowsum, maxkey);

    // ---- layer 2 (BN1 folded inline) ----
    hipLaunchKernelGGL(gemmf_kernel, dim3(gN), dim3(256), 0, stream, hb, sum1, sq1, g1, be1, W2, dinv, zb, N, inv_n);
    hipLaunchKernelGGL(agg_kernel, dim3(gAgg), dim3(256), 0, stream, zb, csr_src, csr_off,
                       dinv, b2, hb, N, 0, sum2, sq2, rowsum, maxkey);

    // ---- layer 3 (BN2 folded inline) ----
    hipLaunchKernelGGL(gemmf_kernel, dim3(gN), dim3(256), 0, stream, hb, sum2, sq2, g2, be2, W3, dinv, zb, N, inv_n);
    hipLaunchKernelGGL(agg_kernel, dim3(gAgg), dim3(256), 0, stream, zb, csr_src, csr_off,
                       dinv, b3, hb, N, 1, sum1, sq1, rowsum, maxkey);

    // ---- pooling + heads ----
    hipLaunchKernelGGL(pool_kernel, dim3(512), dim3(256), 0, stream, hb, rowsum, maxkey, gvec, Zp, N);
    hipLaunchKernelGGL(cand_kernel, dim3(gN), dim3(256), 0, stream, hb, nt, cand_pos,
                       Wc1, bc1, Wc2, bc2, gvec, Zp, Wd1, bd1, Wd2, bd2, out, N, C);
}

// Round 7
// 369.042 us; speedup vs baseline: 1.9960x; 1.0826x over previous
//
#include <hip/hip_runtime.h>
#include <hip/hip_bf16.h>

typedef unsigned int uint;
typedef unsigned short ushort;

#define NB_MAX 256      // max buckets (== blockDim of scan users)
#define NPB_MAX 2048    // max nodes per bucket

// bf16 bit-level conversions (RNE pack, exact unpack) for internal z/h storage
static __device__ __forceinline__ ushort f2b(float f) {
    uint u = __float_as_uint(f);
    uint r = (u + 0x7FFFu + ((u >> 16) & 1u)) >> 16;
    return (ushort)r;
}
static __device__ __forceinline__ float b2f_u(ushort h) { return __uint_as_float(((uint)h) << 16); }

static __device__ __forceinline__ void unpack8(uint4 v, float* o) {
    o[0] = b2f_u(v.x & 0xFFFF); o[1] = b2f_u(v.x >> 16);
    o[2] = b2f_u(v.y & 0xFFFF); o[3] = b2f_u(v.y >> 16);
    o[4] = b2f_u(v.z & 0xFFFF); o[5] = b2f_u(v.z >> 16);
    o[6] = b2f_u(v.w & 0xFFFF); o[7] = b2f_u(v.w >> 16);
}

// ---------------- wave-level inclusive scan (64 lanes) ----------------
static __device__ __forceinline__ unsigned wave_incl_scan(unsigned v) {
    int lane = threadIdx.x & 63;
    #pragma unroll
    for (int d = 1; d < 64; d <<= 1) {
        unsigned t = (unsigned)__shfl_up((int)v, d, 64);
        if (lane >= d) v += t;
    }
    return v;
}

// exclusive block scan: in[0..n) -> out[0..n), n <= 2048, 256 threads, wscr = shared[4]
static __device__ void block_excl_scan(const uint* in, uint* out, int n, uint* wscr) {
    int tid = threadIdx.x;
    int lane = tid & 63, wid = tid >> 6;
    int base = tid * 8;
    uint v[8], pre[8], s = 0;
    #pragma unroll
    for (int k = 0; k < 8; k++) v[k] = (base + k < n) ? in[base + k] : 0u;
    #pragma unroll
    for (int k = 0; k < 8; k++) { pre[k] = s; s += v[k]; }
    uint is = wave_incl_scan(s);
    __syncthreads();                 // protect wscr from previous use
    if (lane == 63) wscr[wid] = is;
    __syncthreads();
    uint woff = 0;
    for (int wI = 0; wI < wid; wI++) woff += wscr[wI];
    uint excl = is - s + woff;
    #pragma unroll
    for (int k = 0; k < 8; k++) if (base + k < n) out[base + k] = excl + pre[k];
    __syncthreads();
}

// ---------------- phase 1: per-bucket edge & candidate histograms ----------------
__global__ __launch_bounds__(256) void bucket_hist_kernel(const int* src, const int* dst,
                                                          const int* nt, uint* bcnt, uint* bcand,
                                                          int E, int N, int NB, int shift) {
    __shared__ uint bh[NB_MAX], ch[NB_MAX];
    int tid = threadIdx.x;
    bh[tid] = 0; ch[tid] = 0;
    __syncthreads();
    int gs = gridDim.x * 256;
    for (int i = blockIdx.x * 256 + tid; i < E; i += gs) {
        int d = dst[i], s = src[i];
        if ((uint)d < (uint)N && (uint)s < (uint)N) atomicAdd(&bh[d >> shift], 1u);
    }
    for (int i = blockIdx.x * 256 + tid; i < N; i += gs) {
        if (nt[i] == 0) atomicAdd(&ch[i >> shift], 1u);
    }
    __syncthreads();
    if (bh[tid]) atomicAdd(&bcnt[tid], bh[tid]);
    if (ch[tid]) atomicAdd(&bcand[tid], ch[tid]);
}

// ---------------- phase 2: partition edges into bucket-contiguous packed staging ----------------
// staging entry: (dst_local << 17) | src   (requires N < 2^17, shift <= 15)
__global__ __launch_bounds__(256) void partition_kernel(const int* src, const int* dst,
                                                        const uint* bcnt, uint* alloc0,
                                                        uint* staging, int E, int N, int shift) {
    __shared__ uint bbase_s[NB_MAX];
    __shared__ uint lh[NB_MAX], gb[NB_MAX];
    __shared__ uint ws4[4];
    int tid = threadIdx.x;
    int lane = tid & 63, wid = tid >> 6;
    // in-block exclusive scan of bcnt -> bbase_s
    uint a = bcnt[tid];
    uint ia = wave_incl_scan(a);
    if (lane == 63) ws4[wid] = ia;
    __syncthreads();
    uint off = 0;
    for (int wI = 0; wI < wid; wI++) off += ws4[wI];
    bbase_s[tid] = ia - a + off;
    lh[tid] = 0;
    __syncthreads();
    int base = blockIdx.x * 2048;
    uint mask = (1u << shift) - 1u;
    int sreg[8], breg[8];
    uint rreg[8], dlreg[8];
    #pragma unroll
    for (int k = 0; k < 8; k++) {
        int e = base + k * 256 + tid;
        breg[k] = -1;
        if (e < E) {
            int s = src[e], d = dst[e];
            if ((uint)d < (uint)N && (uint)s < (uint)N) {
                int b = d >> shift;
                sreg[k] = s; dlreg[k] = (uint)d & mask; breg[k] = b;
                rreg[k] = atomicAdd(&lh[b], 1u);
            }
        }
    }
    __syncthreads();
    gb[tid] = lh[tid] ? (bbase_s[tid] + atomicAdd(&alloc0[tid], lh[tid])) : 0u;
    __syncthreads();
    #pragma unroll
    for (int k = 0; k < 8; k++) {
        if (breg[k] >= 0)
            staging[gb[breg[k]] + rreg[k]] = (dlreg[k] << 17) | (uint)sreg[k];
    }
}

// ---------------- phase 3: per-bucket counting sort + csr_off/dinv/cand_pos + fused gemm1 ----------------
__global__ __launch_bounds__(256) void local_csr_kernel(const uint* staging, const uint* bcnt,
                                                        const uint* bcand, const int* nt,
                                                        const float* x, const float* W1,
                                                        int* csr_src, uint* csr_off, uint* cand_pos,
                                                        float* dinv, ushort* zb,
                                                        int N, int shift, int NB) {
    __shared__ uint deg[NPB_MAX];
    __shared__ uint ofs[NPB_MAX];
    __shared__ uint ws4[4];
    __shared__ uint sb[4];        // ebase, eend, cb
    __shared__ float Ws[96];
    int b = blockIdx.x, tid = threadIdx.x;
    int lane = tid & 63, wid = tid >> 6;
    if (tid < 96) Ws[tid] = W1[tid];
    // scan bcnt -> ebase/eend for bucket b
    uint a = bcnt[tid];
    uint ia = wave_incl_scan(a);
    if (lane == 63) ws4[wid] = ia;
    __syncthreads();
    uint off = 0;
    for (int wI = 0; wI < wid; wI++) off += ws4[wI];
    if (tid == b) { sb[0] = ia - a + off; sb[1] = ia + off; }
    __syncthreads();
    // scan bcand -> cb
    uint c = bcand[tid];
    uint ic = wave_incl_scan(c);
    if (lane == 63) ws4[wid] = ic;
    __syncthreads();
    uint offc = 0;
    for (int wI = 0; wI < wid; wI++) offc += ws4[wI];
    if (tid == b) sb[2] = ic - c + offc;
    __syncthreads();
    uint ebase = sb[0], eend = sb[1], cb = sb[2];
    int nbase = b << shift;
    int ncount = min(1 << shift, N - nbase);
    for (int i = tid; i < ncount; i += 256) deg[i] = 0;
    __syncthreads();
    for (uint p = ebase + tid; p < eend; p += 256)
        atomicAdd(&deg[staging[p] >> 17], 1u);
    __syncthreads();
    block_excl_scan(deg, ofs, ncount, ws4);
    for (int i = tid; i < ncount; i += 256)
        csr_off[nbase + i] = ebase + ofs[i];
    if (b == NB - 1 && tid == 0) csr_off[N] = eend;
    // fused gemm1 + dinv (deg still intact here)
    for (int i = tid; i < ncount; i += 256) {
        int g = nbase + i;
        float di = rsqrtf((float)(deg[i] + 1u));   // +1 self loop
        dinv[g] = di;
        float x0 = x[3 * g], x1 = x[3 * g + 1], x2 = x[3 * g + 2];
        uint pk[16];
        #pragma unroll
        for (int q = 0; q < 16; q++) {
            int j0 = 2 * q, j1 = 2 * q + 1;
            float o0 = (x0 * Ws[j0] + x1 * Ws[32 + j0] + x2 * Ws[64 + j0]) * di;
            float o1 = (x0 * Ws[j1] + x1 * Ws[32 + j1] + x2 * Ws[64 + j1]) * di;
            pk[q] = (uint)f2b(o0) | ((uint)f2b(o1) << 16);
        }
        uint4* zp = (uint4*)(zb + (size_t)g * 32);
        #pragma unroll
        for (int r = 0; r < 4; r++) zp[r] = make_uint4(pk[4*r], pk[4*r+1], pk[4*r+2], pk[4*r+3]);
    }
    __syncthreads();
    for (int i = tid; i < ncount; i += 256) deg[i] = 0;   // reuse as running counters
    __syncthreads();
    for (uint p = ebase + tid; p < eend; p += 256) {
        uint pkv = staging[p];
        uint dl = pkv >> 17;
        uint pos = ebase + ofs[dl] + atomicAdd(&deg[dl], 1u);
        csr_src[pos] = (int)(pkv & 0x1FFFFu);
    }
    __syncthreads();
    for (int i = tid; i < ncount; i += 256) deg[i] = (nt[nbase + i] == 0) ? 1u : 0u;
    __syncthreads();
    block_excl_scan(deg, ofs, ncount, ws4);
    for (int i = tid; i < ncount; i += 256) cand_pos[nbase + i] = cb + ofs[i];
}

// ---------------- folded GEMM with inline BN fold ----------------
__global__ __launch_bounds__(256) void gemmf_kernel(const ushort* hb, const float* stats_sum,
                                                    const float* stats_sq, const float* g,
                                                    const float* be, const float* W,
                                                    const float* dinv, ushort* zb, int n,
                                                    float inv_n) {
    __shared__ float Ws[1024];
    __shared__ float cs[32];
    __shared__ float a_s[32], d_s[32];
    int tid = threadIdx.x;
    if (tid < 32) {
        float mu = stats_sum[tid] * inv_n;
        float var = fmaxf(stats_sq[tid] * inv_n - mu * mu, 0.f);
        float a = g[tid] * rsqrtf(var + 1e-5f);
        a_s[tid] = a;
        d_s[tid] = be[tid] - mu * a;
    }
    __syncthreads();
    #pragma unroll
    for (int t = tid; t < 1024; t += 256) Ws[t] = a_s[t >> 5] * W[t];
    if (tid < 32) {
        float c = 0.f;
        for (int k = 0; k < 32; k++) c += d_s[k] * W[k * 32 + tid];
        cs[tid] = c;
    }
    __syncthreads();
    int i = blockIdx.x * 256 + tid;
    if (i >= n) return;
    const uint4* hp = (const uint4*)(hb + (size_t)i * 32);
    float hk[32];
    #pragma unroll
    for (int r = 0; r < 4; r++) unpack8(hp[r], hk + r * 8);
    float acc[32];
    #pragma unroll
    for (int j = 0; j < 32; j++) acc[j] = cs[j];
    #pragma unroll
    for (int k = 0; k < 32; k++) {
        float h0 = hk[k];
        #pragma unroll
        for (int j = 0; j < 32; j++) acc[j] += h0 * Ws[k * 32 + j];
    }
    float di = dinv[i];
    uint pk[16];
    #pragma unroll
    for (int q = 0; q < 16; q++)
        pk[q] = (uint)f2b(acc[2*q] * di) | ((uint)f2b(acc[2*q+1] * di) << 16);
    uint4* zp = (uint4*)(zb + (size_t)i * 32);
    #pragma unroll
    for (int r = 0; r < 4; r++) zp[r] = make_uint4(pk[4*r], pk[4*r+1], pk[4*r+2], pk[4*r+3]);
}

// ---------------- aggregate: one node per 4-lane quad, 8-way ILP gather batches ----------------
__global__ __launch_bounds__(256) void agg_kernel(const ushort* zb, const int* csr_src,
                                                  const uint* csr_off, const float* dinv,
                                                  const float* bias, ushort* hb, int n,
                                                  int mode, float* stats_sum, float* stats_sq,
                                                  float* rowsum, uint* maxkey) {
    const int tid = threadIdx.x;
    const int wave = tid >> 6;
    const int lane = tid & 63;
    const int c4 = lane & 3;
    const int slot = lane >> 2;
    float bs[8], bq[8];
    #pragma unroll
    for (int j = 0; j < 8; j++) { bs[j] = 0.f; bq[j] = 0.f; }
    float lmax = -3.0e38f;
    int node = (blockIdx.x * 4 + wave) * 16 + slot;
    if (node < n) {
        uint s = csr_off[node], e = csr_off[node + 1];
        float acc[8];
        unpack8(*(const uint4*)(zb + (size_t)node * 32 + c4 * 8), acc);   // self loop
        for (uint p = s; p < e; p += 8) {
            uint idx[8];
            float wg[8];
            #pragma unroll
            for (int j = 0; j < 8; j++) {
                uint q = p + (uint)j;
                uint qc = min(q, e - 1u);
                idx[j] = (uint)csr_src[qc];
                wg[j] = (q < e) ? 1.f : 0.f;
            }
            #pragma unroll
            for (int j = 0; j < 8; j++) {
                float t[8];
                unpack8(*(const uint4*)(zb + (size_t)idx[j] * 32 + c4 * 8), t);
                #pragma unroll
                for (int cI = 0; cI < 8; cI++) acc[cI] = fmaf(wg[j], t[cI], acc[cI]);
            }
        }
        float di = dinv[node];
        float hv[8];
        #pragma unroll
        for (int j = 0; j < 8; j++) hv[j] = fmaxf(di * acc[j] + bias[c4 * 8 + j], 0.f);
        uint4 o;
        o.x = (uint)f2b(hv[0]) | ((uint)f2b(hv[1]) << 16);
        o.y = (uint)f2b(hv[2]) | ((uint)f2b(hv[3]) << 16);
        o.z = (uint)f2b(hv[4]) | ((uint)f2b(hv[5]) << 16);
        o.w = (uint)f2b(hv[6]) | ((uint)f2b(hv[7]) << 16);
        *(uint4*)(hb + (size_t)node * 32 + c4 * 8) = o;
        if (mode == 0) {
            #pragma unroll
            for (int j = 0; j < 8; j++) { bs[j] = hv[j]; bq[j] = hv[j] * hv[j]; }
        } else {
            float rs = ((hv[0] + hv[1]) + (hv[2] + hv[3])) + ((hv[4] + hv[5]) + (hv[6] + hv[7]));
            rs += __shfl_xor(rs, 1, 64);
            rs += __shfl_xor(rs, 2, 64);
            if (c4 == 0) { rowsum[node] = rs; lmax = rs; }
        }
    }
    if (mode == 0) {
        #pragma unroll
        for (int m = 4; m < 64; m <<= 1) {
            #pragma unroll
            for (int j = 0; j < 8; j++) {
                bs[j] += __shfl_xor(bs[j], m, 64);
                bq[j] += __shfl_xor(bq[j], m, 64);
            }
        }
        __shared__ float ssum[4][32], ssq[4][32];
        if (slot == 0) {
            #pragma unroll
            for (int j = 0; j < 8; j++) { ssum[wave][c4 * 8 + j] = bs[j]; ssq[wave][c4 * 8 + j] = bq[j]; }
        }
        __syncthreads();
        if (tid < 32) {
            atomicAdd(&stats_sum[tid], ssum[0][tid] + ssum[1][tid] + ssum[2][tid] + ssum[3][tid]);
            atomicAdd(&stats_sq[tid],  ssq[0][tid] + ssq[1][tid] + ssq[2][tid] + ssq[3][tid]);
        }
    } else {
        #pragma unroll
        for (int m = 1; m < 64; m <<= 1) lmax = fmaxf(lmax, __shfl_xor(lmax, m, 64));
        __shared__ float lm[4];
        if (lane == 0) lm[wave] = lmax;
        __syncthreads();
        if (tid == 0) {
            float m = fmaxf(fmaxf(lm[0], lm[1]), fmaxf(lm[2], lm[3]));
            uint u = __float_as_uint(m);
            uint key = (u & 0x80000000u) ? ~u : (u | 0x80000000u);
            atomicMax(maxkey, key);
        }
    }
}

// ---------------- fused heads: candidate scores + softmax pooling + graph head ----------------
__global__ __launch_bounds__(256) void head_kernel(const ushort* hb, const int* nt,
                                                   const uint* pos, const float* Wc1,
                                                   const float* bc1, const float* Wc2,
                                                   const float* bc2, const float* rowsum,
                                                   const uint* maxkey, float* gvec, float* Zp,
                                                   uint* ticket, const float* Wd1,
                                                   const float* bd1, const float* Wd2,
                                                   const float* bd2, float* out, int n, int C) {
    __shared__ float W1s[512], b1s[16], W2s[16];
    __shared__ float ls[256];
    __shared__ float ge[32], tt[16];
    __shared__ int lastflag;
    int tid = threadIdx.x;
    for (int t = tid; t < 512; t += 256) W1s[t] = Wc1[t];
    if (tid < 16) { b1s[tid] = bc1[tid]; W2s[tid] = Wc2[tid]; }
    __syncthreads();
    // Part A: candidate scores
    int i = blockIdx.x * 256 + tid;
    if (i < n && nt[i] == 0) {
        const uint4* hp = (const uint4*)(hb + (size_t)i * 32);
        float hv[32];
        #pragma unroll
        for (int r = 0; r < 4; r++) unpack8(hp[r], hv + r * 8);
        float s = bc2[0];
        #pragma unroll
        for (int j = 0; j < 16; j++) {
            float u = b1s[j];
            #pragma unroll
            for (int k = 0; k < 32; k++) u += hv[k] * W1s[k * 16 + j];
            s += fmaxf(u, 0.f) * W2s[j];
        }
        s = fminf(fmaxf(s, -1000.f), 1000.f);
        uint p = pos[i];
        if (p < (uint)C) {
            out[p] = s;
            out[C + 1 + p] = (float)i;
        }
    }
    // Part B: pooling partials
    uint key = *maxkey;
    float M = 0.f;
    if (key != 0u) M = (key & 0x80000000u) ? __uint_as_float(key ^ 0x80000000u) : __uint_as_float(~key);
    int lane = tid & 31, grp = tid >> 5;
    int stride = gridDim.x * 8;
    float accZ = 0.f, accg = 0.f;
    for (int node = blockIdx.x * 8 + grp; node < n; node += stride) {
        float ew = __expf(rowsum[node] - M);
        accg += b2f_u(hb[(size_t)node * 32 + lane]) * ew;
        if (lane == 0) accZ += ew;
    }
    ls[tid] = accg;
    __syncthreads();
    if (tid < 32) {
        float a = 0.f;
        #pragma unroll
        for (int g = 0; g < 8; g++) a += ls[tid + 32 * g];
        atomicAdd(&gvec[tid], a);
    }
    __syncthreads();
    ls[tid] = (lane == 0) ? accZ : 0.f;
    __syncthreads();
    if (tid == 0) {
        float a = 0.f;
        for (int t = 0; t < 256; t += 32) a += ls[t];
        atomicAdd(Zp, a);
        __threadfence();
        uint old = atomicAdd(ticket, 1u);
        lastflag = (old == gridDim.x - 1) ? 1 : 0;
    }
    __syncthreads();
    // Part C: last block computes graph head
    if (lastflag) {
        __threadfence();
        if (tid < 32) ge[tid] = atomicAdd(&gvec[tid], 0.f);   // read-through-L2
        if (tid == 0) ls[0] = atomicAdd(Zp, 0.f);
        __syncthreads();
        float Zv = fmaxf(ls[0], 1e-30f);
        if (tid < 32) ge[tid] /= Zv;
        __syncthreads();
        if (tid < 16) {
            float s = bd1[tid];
            for (int k = 0; k < 32; k++) s += ge[k] * Wd1[k * 16 + tid];
            tt[tid] = fmaxf(s, 0.f);
        }
        __syncthreads();
        if (tid == 0) {
            float s = bd2[0];
            for (int j = 0; j < 16; j++) s += tt[j] * Wd2[j];
            out[C] = fminf(fmaxf(s, -1000.f), 1000.f);
        }
    }
}

// ---------------- host launch ----------------
extern "C" void kernel_launch(void* const* d_in, const int* in_sizes, int n_in,
                              void* d_out, int out_size, void* d_ws, size_t ws_size,
                              hipStream_t stream) {
    const float* x   = (const float*)d_in[0];
    const int*   ei  = (const int*)d_in[1];
    const int*   nt  = (const int*)d_in[2];
    const float* W1  = (const float*)d_in[3];  const float* b1  = (const float*)d_in[4];
    const float* W2  = (const float*)d_in[5];  const float* b2  = (const float*)d_in[6];
    const float* W3  = (const float*)d_in[7];  const float* b3  = (const float*)d_in[8];
    const float* g1  = (const float*)d_in[9];  const float* be1 = (const float*)d_in[10];
    const float* g2  = (const float*)d_in[11]; const float* be2 = (const float*)d_in[12];
    const float* Wc1 = (const float*)d_in[13]; const float* bc1 = (const float*)d_in[14];
    const float* Wc2 = (const float*)d_in[15]; const float* bc2 = (const float*)d_in[16];
    const float* Wd1 = (const float*)d_in[17]; const float* bd1 = (const float*)d_in[18];
    const float* Wd2 = (const float*)d_in[19]; const float* bd2 = (const float*)d_in[20];

    const int N = in_sizes[0] / 3;
    const int E = in_sizes[1] / 2;
    const int C = (out_size - 1) / 2;
    const int* e_src = ei;
    const int* e_dst = ei + E;
    float* out = (float*)d_out;

    // bucket geometry: nodes/bucket = 1<<shift, NB <= 256 (packing needs N < 2^17)
    int shift = 9;
    while (((N + (1 << shift) - 1) >> shift) > NB_MAX) shift++;
    const int NB = (N + (1 << shift) - 1) >> shift;

    // ---- workspace carve-up ----
    char* w = (char*)d_ws;
    auto alloc = [&](size_t bytes) { void* p = (void*)w; w += (bytes + 255) & ~(size_t)255; return p; };
    float*    stats  = (float*)alloc(256 * 4);     // zeroed
    uint*     bcnt   = (uint*)alloc(NB_MAX * 4);   // zeroed
    uint*     bcand  = (uint*)alloc(NB_MAX * 4);   // zeroed
    uint*     alloc0 = (uint*)alloc(NB_MAX * 4);   // zeroed
    size_t zero_bytes = (size_t)((char*)w - (char*)stats);
    float*    dinv   = (float*)alloc((size_t)N * 4);
    uint*     csr_off= (uint*)alloc((size_t)(N + 1) * 4);
    uint*     cand_pos=(uint*)alloc((size_t)N * 4);
    float*    rowsum = (float*)alloc((size_t)N * 4);
    int*      csr_src= (int*)alloc((size_t)E * 4);
    ushort*   zb     = (ushort*)alloc((size_t)N * 32 * 2);
    ushort*   hb     = (ushort*)alloc((size_t)N * 32 * 2);
    // packed staging (E * 4 B) aliases hb (dead until agg layer-1 writes it)
    uint*     staging = (uint*)hb;

    float* sum1 = stats;       float* sq1 = stats + 32;
    float* sum2 = stats + 64;  float* sq2 = stats + 96;
    float* gvec = stats + 128; float* Zp  = stats + 160;
    uint* maxkey = (uint*)(stats + 161);
    uint* ticket = (uint*)(stats + 162);

    hipMemsetAsync(stats, 0, zero_bytes, stream);

    const int gN   = (N + 255) / 256;
    const int gPar = (E + 2047) / 2048;
    const int gAgg = (N + 63) / 64;
    const float inv_n = 1.0f / (float)N;

    // ---- CSR build (XCD-local two-phase counting sort, packed staging) ----
    hipLaunchKernelGGL(bucket_hist_kernel, dim3(784), dim3(256), 0, stream, e_src, e_dst, nt, bcnt, bcand, E, N, NB, shift);
    hipLaunchKernelGGL(partition_kernel, dim3(gPar), dim3(256), 0, stream, e_src, e_dst, bcnt, alloc0, staging, E, N, shift);
    hipLaunchKernelGGL(local_csr_kernel, dim3(NB), dim3(256), 0, stream, staging, bcnt, bcand, nt,
                       x, W1, csr_src, csr_off, cand_pos, dinv, zb, N, shift, NB);

    // ---- layer 1 ----
    hipLaunchKernelGGL(agg_kernel, dim3(gAgg), dim3(256), 0, stream, zb, csr_src, csr_off,
                       dinv, b1, hb, N, 0, sum1, sq1, rowsum, maxkey);

    // ---- layer 2 (BN1 folded inline) ----
    hipLaunchKernelGGL(gemmf_kernel, dim3(gN), dim3(256), 0, stream, hb, sum1, sq1, g1, be1, W2, dinv, zb, N, inv_n);
    hipLaunchKernelGGL(agg_kernel, dim3(gAgg), dim3(256), 0, stream, zb, csr_src, csr_off,
                       dinv, b2, hb, N, 0, sum2, sq2, rowsum, maxkey);

    // ---- layer 3 (BN2 folded inline) ----
    hipLaunchKernelGGL(gemmf_kernel, dim3(gN), dim3(256), 0, stream, hb, sum2, sq2, g2, be2, W3, dinv, zb, N, inv_n);
    hipLaunchKernelGGL(agg_kernel, dim3(gAgg), dim3(256), 0, stream, zb, csr_src, csr_off,
                       dinv, b3, hb, N, 1, sum1, sq1, rowsum, maxkey);

    // ---- fused heads ----
    hipLaunchKernelGGL(head_kernel, dim3(gN), dim3(256), 0, stream, hb, nt, cand_pos,
                       Wc1, bc1, Wc2, bc2, rowsum, maxkey, gvec, Zp, ticket,
                       Wd1, bd1, Wd2, bd2, out, N, C);
}